// Round 17
// baseline (41.327 us; speedup 1.0000x reference)
//
#include <hip/hip_runtime.h>
#include <hip/hip_fp16.h>

#define NCITY 384
#define BATCH 4
#define DIM   128
#define HID   256
#define M_TOT 1536

typedef unsigned short u16;

// ---------------------------------------------------------------------------
// packed f16 helpers (raw VOP3P; ROCm header __hmax2 broken on gfx950)
// ---------------------------------------------------------------------------
__device__ __forceinline__ unsigned pk_add(unsigned a, unsigned b) {
    unsigned r; asm("v_pk_add_f16 %0, %1, %2" : "=v"(r) : "v"(a), "v"(b)); return r;
}
__device__ __forceinline__ unsigned pk_max0(unsigned a) {
    unsigned r; asm("v_pk_max_f16 %0, %1, %2" : "=v"(r) : "v"(a), "v"(0u)); return r;
}
__device__ __forceinline__ unsigned pk_fma(unsigned a, unsigned b, unsigned c) {
    unsigned r; asm("v_pk_fma_f16 %0, %1, %2, %3" : "=v"(r) : "v"(a), "v"(b), "v"(c)); return r;
}
__device__ __forceinline__ unsigned pack2(float a, float b) {
    union { __half2 h2; unsigned u; } c;
    c.h2 = __float22half2_rn(make_float2(a, b));
    return c.u;
}
__device__ __forceinline__ float sum2(unsigned u) {
    union { unsigned u; __half2 h2; } c; c.u = u;
    return __low2float(c.h2) + __high2float(c.h2);
}
__device__ __forceinline__ u16 h_bits(float x) {
    union { __half h; u16 s; } c;
    c.h = __float2half(x);
    return c.s;
}
union H8 { float4 f4; unsigned u[4]; };

// ---------------------------------------------------------------------------
// K1: emb burst-tile. Block = 8 rows x 64 dims; grid (2, 192); 72 KB LDS ->
// 2 blocks/CU. Stage = 16 INDEPENDENT float4 loads/thread issued before h1
// compute (latency hidden under it); ONE barrier; pure-LDS compute.
// ---------------------------------------------------------------------------
__global__ __launch_bounds__(256, 2) void emb_burst(
    const float* __restrict__ cities,
    const float* __restrict__ We1, const float* __restrict__ be1,
    const float* __restrict__ We2, const float* __restrict__ be2,
    float* __restrict__ emb)
{
    __shared__ float Bs[256 * 64];   // 64 KB  [k][64]
    __shared__ float h1[8 * 256];    // 8 KB   [r][256]

    const int tid = threadIdx.x;
    const int d0  = blockIdx.x * 64;
    const int r0  = blockIdx.y * 8;

    // issue the weight-slice burst FIRST (16 independent loads)
    const int c16 = tid & 15;        // float4 col within slice
    const int kr  = tid >> 4;        // 16 k-phases
    float4 breg[16];
    #pragma unroll
    for (int i = 0; i < 16; ++i)
        breg[i] = *(const float4*)&We2[(kr + i * 16) * DIM + d0 + c16 * 4];

    // h1 for 8 rows — overlaps the burst latency
    {
        const float w0 = We1[tid], w1 = We1[HID + tid], b1v = be1[tid];
        #pragma unroll
        for (int r = 0; r < 8; ++r) {
            const float cx = cities[(r0 + r) * 2];
            const float cy = cities[(r0 + r) * 2 + 1];
            h1[r * HID + tid] = fmaxf(fmaf(cx, w0, fmaf(cy, w1, b1v)), 0.f);
        }
    }
    #pragma unroll
    for (int i = 0; i < 16; ++i)
        *(float4*)&Bs[(kr + i * 16) * 64 + c16 * 4] = breg[i];
    __syncthreads();

    // compute: thread (r = tid>>5, c2 = tid&31) -> float2 out
    const int r  = tid >> 5;
    const int c2 = tid & 31;
    float2 acc = {0.f, 0.f};
    #pragma unroll 4
    for (int k4 = 0; k4 < 64; ++k4) {
        const float4 a4 = *(const float4*)&h1[r * HID + k4 * 4];
        #pragma unroll
        for (int kk = 0; kk < 4; ++kk) {
            const float2 b = *(const float2*)&Bs[(k4 * 4 + kk) * 64 + c2 * 2];
            const float a = (&a4.x)[kk];
            acc.x = fmaf(a, b.x, acc.x);
            acc.y = fmaf(a, b.y, acc.y);
        }
    }
    const float2 be2v = *(const float2*)&be2[d0 + c2 * 2];
    acc.x += be2v.x;
    acc.y += be2v.y;
    *(float2*)&emb[(r0 + r) * DIM + d0 + c2 * 2] = acc;
}

// ---------------------------------------------------------------------------
// K2: heads burst-tile. Block = 16 rows x 128 cols; grid (6, 96) = 576 blocks;
// 72 KB LDS -> 2 blocks/CU. One stage burst (16+2 float4/thread), one barrier,
// LDS compute, per-segment epilogue. f32 math; Ai/Aj written f16.
// g 0-1: att cols (relu*wa2 partial-reduce -> score_part[g]);
// g 2-3: Ai cols (+bd1); g 4-5: Aj cols.
// ---------------------------------------------------------------------------
__global__ __launch_bounds__(256, 2) void heads_burst(
    const float* __restrict__ emb,
    const float* __restrict__ Wa1, const float* __restrict__ Wd1,
    const float* __restrict__ ba1, const float* __restrict__ wa2,
    const float* __restrict__ bd1,
    float* __restrict__ score_part,
    u16* __restrict__ Ai_u, u16* __restrict__ Aj_u)
{
    __shared__ float As[16 * 128];    // 8 KB  [r][k]
    __shared__ float Bs[128 * 128];   // 64 KB [k][c]

    const int tid = threadIdx.x;
    const int g   = blockIdx.x;       // 0..5
    const int m0  = blockIdx.y * 16;

    const float* Bsrc;
    int c0;
    if (g < 2)      { Bsrc = Wa1;             c0 = g * 128; }
    else if (g < 4) { Bsrc = Wd1;             c0 = (g - 2) * 128; }
    else            { Bsrc = Wd1 + DIM * HID; c0 = (g - 4) * 128; }

    {   // stage B: 16 independent float4/thread
        const int cq = tid & 31, kr = tid >> 5;
        #pragma unroll
        for (int i = 0; i < 16; ++i) {
            const int k = kr + i * 8;
            *(float4*)&Bs[k * 128 + cq * 4] =
                *(const float4*)&Bsrc[k * HID + c0 + cq * 4];
        }
    }
    {   // stage A: 2 independent float4/thread
        const int r = tid & 15, q = tid >> 4;
        #pragma unroll
        for (int i = 0; i < 2; ++i) {
            const int qq = q + i * 16;
            *(float4*)&As[r * 128 + qq * 4] =
                *(const float4*)&emb[(m0 + r) * DIM + qq * 4];
        }
    }
    __syncthreads();

    // compute: thread (r = tid>>4, cq = tid&15) -> quads {cq, cq+16}
    const int r  = tid >> 4;
    const int cq = tid & 15;
    float4 acc0 = {0.f, 0.f, 0.f, 0.f};
    float4 acc1 = {0.f, 0.f, 0.f, 0.f};
    #pragma unroll 4
    for (int k4 = 0; k4 < 32; ++k4) {
        const float4 a4 = *(const float4*)&As[r * 128 + k4 * 4];
        #pragma unroll
        for (int kk = 0; kk < 4; ++kk) {
            const int k = k4 * 4 + kk;
            const float a = (&a4.x)[kk];
            const float4 b0 = *(const float4*)&Bs[k * 128 + cq * 4];
            const float4 b1 = *(const float4*)&Bs[k * 128 + (cq + 16) * 4];
            acc0.x = fmaf(a, b0.x, acc0.x);
            acc0.y = fmaf(a, b0.y, acc0.y);
            acc0.z = fmaf(a, b0.z, acc0.z);
            acc0.w = fmaf(a, b0.w, acc0.w);
            acc1.x = fmaf(a, b1.x, acc1.x);
            acc1.y = fmaf(a, b1.y, acc1.y);
            acc1.z = fmaf(a, b1.z, acc1.z);
            acc1.w = fmaf(a, b1.w, acc1.w);
        }
    }

    if (g < 2) {
        const float4 ba0 = *(const float4*)&ba1[c0 + cq * 4];
        const float4 ba1v = *(const float4*)&ba1[c0 + (cq + 16) * 4];
        const float4 wa0 = *(const float4*)&wa2[c0 + cq * 4];
        const float4 wa1v = *(const float4*)&wa2[c0 + (cq + 16) * 4];
        float s = fmaxf(acc0.x + ba0.x, 0.f) * wa0.x
                + fmaxf(acc0.y + ba0.y, 0.f) * wa0.y
                + fmaxf(acc0.z + ba0.z, 0.f) * wa0.z
                + fmaxf(acc0.w + ba0.w, 0.f) * wa0.w
                + fmaxf(acc1.x + ba1v.x, 0.f) * wa1v.x
                + fmaxf(acc1.y + ba1v.y, 0.f) * wa1v.y
                + fmaxf(acc1.z + ba1v.z, 0.f) * wa1v.z
                + fmaxf(acc1.w + ba1v.w, 0.f) * wa1v.w;
        s += __shfl_xor(s, 1);
        s += __shfl_xor(s, 2);
        s += __shfl_xor(s, 4);
        s += __shfl_xor(s, 8);
        if (cq == 0)
            score_part[g * M_TOT + m0 + r] = s;
    } else {
        u16* dst = (g < 4) ? Ai_u : Aj_u;
        const int cc = (g < 4) ? (g - 2) * 128 : (g - 4) * 128;
        float4 o0 = acc0, o1 = acc1;
        if (g < 4) {
            const float4 b0 = *(const float4*)&bd1[cc + cq * 4];
            const float4 b1 = *(const float4*)&bd1[cc + (cq + 16) * 4];
            o0.x += b0.x; o0.y += b0.y; o0.z += b0.z; o0.w += b0.w;
            o1.x += b1.x; o1.y += b1.y; o1.z += b1.z; o1.w += b1.w;
        }
        uint2 p0, p1;
        p0.x = (unsigned)h_bits(o0.x) | ((unsigned)h_bits(o0.y) << 16);
        p0.y = (unsigned)h_bits(o0.z) | ((unsigned)h_bits(o0.w) << 16);
        p1.x = (unsigned)h_bits(o1.x) | ((unsigned)h_bits(o1.y) << 16);
        p1.y = (unsigned)h_bits(o1.z) | ((unsigned)h_bits(o1.w) << 16);
        *(uint2*)&dst[(m0 + r) * HID + cc + cq * 4] = p0;
        *(uint2*)&dst[(m0 + r) * HID + cc + (cq + 16) * 4] = p1;
    }
}

// ---------------------------------------------------------------------------
// K3: pairwise decoder (f16) + fused softmax summing 2 score partials.
// Verbatim R15 (proven, absmax 0.0). grid (145, 4).
// ---------------------------------------------------------------------------
__global__ __launch_bounds__(256) void pair_sm_kernel(
    const __half* __restrict__ Ai, const __half* __restrict__ Aj,
    const float* __restrict__ wd2, const float* __restrict__ bd2,
    const float* __restrict__ sp, float* __restrict__ att,
    float* __restrict__ p)
{
    const int tid = threadIdx.x;
    const int b   = blockIdx.y;

    if (blockIdx.x == 144) {     // ---- softmax block for batch b ------------
        __shared__ float red[8];
        const int t = tid;
        const float v0 = sp[b * NCITY + t] + sp[M_TOT + b * NCITY + t];
        const bool  h2v = (t < NCITY - 256);
        const float v1 = h2v ? (sp[b * NCITY + 256 + t] + sp[M_TOT + b * NCITY + 256 + t])
                             : -3.4e38f;
        float m = fmaxf(v0, v1);
        #pragma unroll
        for (int off = 32; off > 0; off >>= 1)
            m = fmaxf(m, __shfl_down(m, off));
        if ((t & 63) == 0) red[t >> 6] = m;
        __syncthreads();
        m = fmaxf(fmaxf(red[0], red[1]), fmaxf(red[2], red[3]));
        const float e0 = __expf(v0 - m);
        const float e1 = h2v ? __expf(v1 - m) : 0.f;
        float s = e0 + e1;
        #pragma unroll
        for (int off = 32; off > 0; off >>= 1)
            s += __shfl_down(s, off);
        if ((t & 63) == 0) red[4 + (t >> 6)] = s;
        __syncthreads();
        s = red[4] + red[5] + red[6] + red[7];
        att[b * NCITY + t] = e0 / s;
        if (h2v) att[b * NCITY + 256 + t] = e1 / s;
        return;
    }

    __shared__ __half ai_s[32 * HID];    // 16 KB
    __shared__ __half aj_s[32 * HID];    // 16 KB
    __shared__ unsigned wd2h[HID / 2];   // 512 B

    const int i0 = (blockIdx.x / 12) * 32;
    const int j0 = (blockIdx.x % 12) * 32;

    if (tid < HID / 2) {
        const float2 w2 = *(const float2*)&wd2[tid * 2];
        wd2h[tid] = pack2(w2.x, w2.y);
    }

    for (int u = tid; u < 32 * 32; u += 256) {
        const int r = u >> 5, s = u & 31;
        const int su = (s ^ (r & 15)) * 8;
        *(float4*)&ai_s[r * HID + su] =
            *(const float4*)&Ai[(b * NCITY + i0 + r) * HID + s * 8];
        *(float4*)&aj_s[r * HID + su] =
            *(const float4*)&Aj[(b * NCITY + j0 + r) * HID + s * 8];
    }
    __syncthreads();

    const int tx = tid & 15;
    const int ty = tid >> 4;

    unsigned a00A = 0u, a00B = 0u, a01A = 0u, a01B = 0u;
    unsigned a10A = 0u, a10B = 0u, a11A = 0u, a11B = 0u;

    #pragma unroll 4
    for (int k8 = 0; k8 < 32; ++k8) {
        const int ci = (k8 ^ ty) * 8;
        const int cj = (k8 ^ tx) * 8;
        H8 x0, x1, y0, y1;
        x0.f4 = *(const float4*)&ai_s[ ty       * HID + ci];
        x1.f4 = *(const float4*)&ai_s[(ty + 16) * HID + ci];
        y0.f4 = *(const float4*)&aj_s[ tx       * HID + cj];
        y1.f4 = *(const float4*)&aj_s[(tx + 16) * HID + cj];

        #pragma unroll
        for (int q = 0; q < 4; ++q) {
            const unsigned w = wd2h[k8 * 4 + q];
            const unsigned t00 = pk_max0(pk_add(x0.u[q], y0.u[q]));
            const unsigned t01 = pk_max0(pk_add(x0.u[q], y1.u[q]));
            const unsigned t10 = pk_max0(pk_add(x1.u[q], y0.u[q]));
            const unsigned t11 = pk_max0(pk_add(x1.u[q], y1.u[q]));
            if (q < 2) {
                a00A = pk_fma(t00, w, a00A);
                a01A = pk_fma(t01, w, a01A);
                a10A = pk_fma(t10, w, a10A);
                a11A = pk_fma(t11, w, a11A);
            } else {
                a00B = pk_fma(t00, w, a00B);
                a01B = pk_fma(t01, w, a01B);
                a10B = pk_fma(t10, w, a10B);
                a11B = pk_fma(t11, w, a11B);
            }
        }
    }

    const float bd = bd2[0];
    float accs[2][2];
    accs[0][0] = sum2(a00A) + sum2(a00B);
    accs[0][1] = sum2(a01A) + sum2(a01B);
    accs[1][0] = sum2(a10A) + sum2(a10B);
    accs[1][1] = sum2(a11A) + sum2(a11B);

    #pragma unroll
    for (int ii = 0; ii < 2; ++ii) {
        #pragma unroll
        for (int jj = 0; jj < 2; ++jj) {
            const int gi = i0 + ty + ii * 16;
            const int gj = j0 + tx + jj * 16;
            const float v = 1.f / (1.f + __expf(-(accs[ii][jj] + bd)));
            p[(b * NCITY + gi) * NCITY + gj] = (gi == gj) ? 0.f : v;
        }
    }
}

// ---------------------------------------------------------------------------
extern "C" void kernel_launch(void* const* d_in, const int* in_sizes, int n_in,
                              void* d_out, int out_size, void* d_ws, size_t ws_size,
                              hipStream_t stream)
{
    const float* cities = (const float*)d_in[0];
    const float* We1    = (const float*)d_in[1];
    const float* be1    = (const float*)d_in[2];
    const float* We2    = (const float*)d_in[3];
    const float* be2    = (const float*)d_in[4];
    const float* Wa1    = (const float*)d_in[5];
    const float* ba1    = (const float*)d_in[6];
    const float* wa2    = (const float*)d_in[7];
    const float* ba2    = (const float*)d_in[8];
    const float* Wd1    = (const float*)d_in[9];
    const float* bd1    = (const float*)d_in[10];
    const float* wd2    = (const float*)d_in[11];
    const float* bd2    = (const float*)d_in[12];
    (void)ba2;   // softmax shift-invariant

    float* out_att = (float*)d_out;                 // [4,384]
    float* out_p   = out_att + M_TOT;               // [4,384,384]

    float* score_part = (float*)d_ws;                     // 2*1536 f32
    float* emb        = score_part + 2 * M_TOT;           // 1536*128 f32
    u16*   Ai_u       = (u16*)(emb + M_TOT * DIM);        // 1536*256 u16
    u16*   Aj_u       = Ai_u + M_TOT * HID;               // 1536*256 u16

    emb_burst<<<dim3(2, 192), 256, 0, stream>>>(
        cities, We1, be1, We2, be2, emb);

    heads_burst<<<dim3(6, 96), 256, 0, stream>>>(
        emb, Wa1, Wd1, ba1, wa2, bd1, score_part, Ai_u, Aj_u);

    pair_sm_kernel<<<dim3(145, BATCH), 256, 0, stream>>>(
        (const __half*)Ai_u, (const __half*)Aj_u, wd2, bd2,
        score_part, out_att, out_p);
}